// Round 12
// baseline (93.340 us; speedup 1.0000x reference)
//
#include <hip/hip_runtime.h>
#include <hip/hip_bf16.h>
#include <stdint.h>

#define BROWS 16384
#define DIM   256
#define BM    128               // A rows per block (persistent in registers)
#define NBM   (BROWS / BM)      // 128 row blocks
#define NBNR  8                 // col-range blocks; each covers 16 tiles x 128
#define NCHUNK 16               // per-row partial chunks (8 bnr x 2 wc)

#define LOG2E 1.44269504088896340736f

typedef __attribute__((ext_vector_type(8))) int  i32x8;
typedef __attribute__((ext_vector_type(4))) float f32x4;
typedef unsigned char uchar;

#if __has_builtin(__builtin_amdgcn_exp2f)
#define EXP2(x) __builtin_amdgcn_exp2f(x)   // bare v_exp_f32; |arg|<=1.45 -> exact
#else
#define EXP2(x) exp2f(x)
#endif

// Tiled fp8 layout ("frag-major", HW-verified r10/r11): row r, byte (c*32+b):
//   addr = (r>>4)*4096 + c*512 + (r&15)*32 + b
// Wave frag load (lane l: row 16g+(l&15), K-chunk kt*4+(l>>4)) =
//   g*4096 + kt*2048 + l*32  -> 2KB contiguous, perfectly coalesced.

// ---------------- Kernel A: normalize BOTH matrices -> tiled fp8 + diag -----
__global__ void normalize_both(const float* __restrict__ o,
                               const float* __restrict__ t,
                               uchar* __restrict__ o8,
                               uchar* __restrict__ t8,
                               float* __restrict__ dlog) {
  int row  = blockIdx.x * 4 + (threadIdx.x >> 6);
  int lane = threadIdx.x & 63;
  float4 a = *(reinterpret_cast<const float4*>(o + (size_t)row * DIM) + lane);
  float4 b = *(reinterpret_cast<const float4*>(t + (size_t)row * DIM) + lane);
  float sso = a.x * a.x + a.y * a.y + a.z * a.z + a.w * a.w;
  float sst = b.x * b.x + b.y * b.y + b.z * b.z + b.w * b.w;
  float d   = a.x * b.x + a.y * b.y + a.z * b.z + a.w * b.w;
#pragma unroll
  for (int m = 1; m < 64; m <<= 1) {
    sso += __shfl_xor(sso, m);
    sst += __shfl_xor(sst, m);
    d   += __shfl_xor(d, m);
  }
  float ro = rsqrtf(sso);
  float rt = rsqrtf(sst);
  if (lane == 0) dlog[row] = d * ro * rt;
  float qo = ro * LOG2E;
  int wo = 0, wt = 0;
  wo = __builtin_amdgcn_cvt_pk_fp8_f32(a.x * qo, a.y * qo, wo, false);
  wo = __builtin_amdgcn_cvt_pk_fp8_f32(a.z * qo, a.w * qo, wo, true);
  wt = __builtin_amdgcn_cvt_pk_fp8_f32(b.x * rt, b.y * rt, wt, false);
  wt = __builtin_amdgcn_cvt_pk_fp8_f32(b.z * rt, b.w * rt, wt, true);
  size_t taddr = (size_t)(row >> 4) * 4096 + (size_t)((lane >> 3) * 512) +
                 (size_t)((row & 15) * 32) + (size_t)((lane & 7) * 4);
  *reinterpret_cast<int*>(o8 + taddr) = wo;
  *reinterpret_cast<int*>(t8 + taddr) = wt;
}

// ---------------- Kernel B: persistent-A fp8 GEMM + exp2 + fused row sums ---
// Block = 128 A-rows x 2048 cols; 8 waves (4 wr x 2 wc), wave tile 32x64.
// Per-wave state ~100 regs: af[2][2]=32 (persistent A), rolling 2-slot B
// buffer bX/bY (32), v[8] row-sums, transient acc. launch_bounds(512,4)
// -> 4 waves/SIMD (the r11 limiter was 2). NO LDS, NO barriers: B ping-pongs
// at n-step granularity (load next while computing current, 64 steps).
// Frag (HW-verified r5/r6/r10/r11): lane l holds row (l&15), K [(l>>4)*32).
// C/D: col = lane&15, row = (lane>>4)*4 + reg.
__global__ __launch_bounds__(512, 4) void gemm_expsum(
    const uchar* __restrict__ A8,   // ohat fp8 tiled, pre-scaled by log2e
    const uchar* __restrict__ B8,   // that fp8 tiled (rows = logits cols)
    float* __restrict__ partial) {
  // XCD-partitioned: xcd owns a contiguous 16-entry bm strip; consecutive ids
  // share bnr -> concurrent blocks on an XCD reuse the same 512KB B strip in L2.
  int b   = blockIdx.x;
  int xcd = b & 7;
  int idx = b >> 3;               // 0..127
  int bm  = xcd * 16 + (idx & 15);
  int bnr = idx >> 4;             // 0..7

  int tid  = threadIdx.x;
  int lane = tid & 63;
  int wid  = tid >> 6;            // 0..7
  int wr   = wid >> 1;            // 0..3 (32-row strip)
  int wc   = wid & 1;             // 0..1 (64-col strip)

  const uchar* Ap = A8 + (size_t)(bm * 8 + wr * 2) * 4096 + (size_t)lane * 32;
  const uchar* Bp = B8 + (size_t)(bnr * 128 + wc * 4) * 4096 + (size_t)lane * 32;

  // persistent A fragments (32 regs)
  i32x8 af[2][2];
#pragma unroll
  for (int m = 0; m < 2; ++m)
#pragma unroll
    for (int kt = 0; kt < 2; ++kt)
      af[m][kt] = *reinterpret_cast<const i32x8*>(Ap + m * 4096 + kt * 2048);

  float v[8];
#pragma unroll
  for (int j = 0; j < 8; ++j) v[j] = 0.f;

  const f32x4 zero4 = {0.f, 0.f, 0.f, 0.f};

#define LOADN(dst, t, n)                                                       \
  {                                                                            \
    dst[0] = *reinterpret_cast<const i32x8*>(Bp + (size_t)(t) * 32768 +        \
                                             (n) * 4096);                      \
    dst[1] = *reinterpret_cast<const i32x8*>(Bp + (size_t)(t) * 32768 +        \
                                             (n) * 4096 + 2048);               \
  }

#define COMP(cur)                                                              \
  {                                                                            \
    _Pragma("unroll") for (int m = 0; m < 2; ++m) {                            \
      f32x4 acc = __builtin_amdgcn_mfma_scale_f32_16x16x128_f8f6f4(            \
          af[m][0], cur[0], zero4, 0, 0, 0, 0x7F7F7F7F, 0, 0x7F7F7F7F);        \
      acc = __builtin_amdgcn_mfma_scale_f32_16x16x128_f8f6f4(                  \
          af[m][1], cur[1], acc, 0, 0, 0, 0x7F7F7F7F, 0, 0x7F7F7F7F);          \
      v[m * 4 + 0] += EXP2(acc[0]);                                            \
      v[m * 4 + 1] += EXP2(acc[1]);                                            \
      v[m * 4 + 2] += EXP2(acc[2]);                                            \
      v[m * 4 + 3] += EXP2(acc[3]);                                            \
    }                                                                          \
  }

  i32x8 bX[2], bY[2];
  LOADN(bX, 0, 0);
#pragma unroll
  for (int t = 0; t < 16; ++t) {
    LOADN(bY, t, 1);
    COMP(bX);                      // n=0
    LOADN(bX, t, 2);
    COMP(bY);                      // n=1
    LOADN(bY, t, 3);
    COMP(bX);                      // n=2
    if (t < 15) LOADN(bX, t + 1, 0);
    COMP(bY);                      // n=3
  }
#undef LOADN
#undef COMP

  // ---- bisect butterfly: v[8] over the 16 fragment columns ----
#pragma unroll
  for (int s = 0; s < 3; ++s) {
    const int len = 8 >> s;
    const int bit = (lane >> s) & 1;
#pragma unroll
    for (int t = 0; t < 4; ++t) {
      if (t < (len >> 1)) {
        float a = v[2 * t], b2 = v[2 * t + 1];
        float recv = __shfl_xor(bit ? a : b2, 1 << s);
        v[t] = (bit ? b2 : a) + recv;
      }
    }
  }
  v[0] += __shfl_xor(v[0], 8);   // complete the 16-lane column sum
  if ((lane & 8) == 0) {
    int j     = lane & 7;        // m = j>>2, r = j&3
    int sub   = lane >> 4;       // 0..3
    int row   = bm * BM + wr * 32 + (j >> 2) * 16 + sub * 4 + (j & 3);
    int chunk = (bnr << 1) | wc;
    partial[(size_t)row * NCHUNK + chunk] = v[0];
  }
}

// ---------------- Kernel C: per-row finish: log(sum) - exact diag ----------
__global__ void row_finish(const float* __restrict__ partial,
                           const float* __restrict__ dlog,
                           float* __restrict__ rowloss) {
  int tid = threadIdx.x;
  int row = blockIdx.x * 64 + (tid >> 2);
  int q   = tid & 3;
  float4 p = reinterpret_cast<const float4*>(partial + (size_t)row * NCHUNK)[q];
  float s = p.x + p.y + p.z + p.w;
  s += __shfl_xor(s, 1);
  s += __shfl_xor(s, 2);
  if (q == 0) rowloss[row] = logf(s) - dlog[row];
}

// ---------------- Kernel D: mean over rows -> d_out[0] ----------------
__global__ void final_reduce(const float* __restrict__ rl, float* __restrict__ out) {
  __shared__ float sm[16];
  float s = 0.f;
  for (int i = threadIdx.x; i < BROWS; i += 1024) s += rl[i];
#pragma unroll
  for (int m = 1; m < 64; m <<= 1) s += __shfl_xor(s, m);
  int wid = threadIdx.x >> 6, lane = threadIdx.x & 63;
  if (lane == 0) sm[wid] = s;
  __syncthreads();
  if (wid == 0) {
    float v = (lane < 16) ? sm[lane] : 0.f;
#pragma unroll
    for (int m = 1; m < 16; m <<= 1) v += __shfl_xor(v, m);
    if (lane == 0) out[0] = v / (float)BROWS;
  }
}

extern "C" void kernel_launch(void* const* d_in, const int* in_sizes, int n_in,
                              void* d_out, int out_size, void* d_ws, size_t ws_size,
                              hipStream_t stream) {
  const float* outputs = (const float*)d_in[0];
  const float* targets = (const float*)d_in[1];
  float* out = (float*)d_out;
  char* ws = (char*)d_ws;

  uchar* o8      = (uchar*)ws;                                      // 4 MB (tiled)
  uchar* t8      = (uchar*)(ws + (size_t)4 * 1024 * 1024);          // 4 MB (tiled)
  float* partial = (float*)(ws + (size_t)8 * 1024 * 1024);          // 1 MB
  float* dlog    = (float*)(ws + (size_t)10 * 1024 * 1024);         // 64 KB
  float* rowloss = (float*)(ws + (size_t)10 * 1024 * 1024 + 65536); // 64 KB

  normalize_both<<<BROWS / 4, 256, 0, stream>>>(outputs, targets, o8, t8, dlog);
  gemm_expsum<<<NBM * NBNR, 512, 0, stream>>>(o8, t8, partial);
  row_finish<<<BROWS / 64, 256, 0, stream>>>(partial, dlog, rowloss);
  final_reduce<<<1, 1024, 0, stream>>>(rowloss, out);
}

// Round 13
// 79.543 us; speedup vs baseline: 1.1735x; 1.1735x over previous
//
#include <hip/hip_runtime.h>
#include <hip/hip_bf16.h>
#include <stdint.h>

#define BROWS 16384
#define DIM   256
#define BM    128               // A rows per block (persistent in registers)
#define NBM   (BROWS / BM)      // 128 row blocks
#define NBNR  8                 // col-range blocks; each covers 16 tiles x 128
#define NTILE 16
#define NCHUNK 16               // per-row partial chunks (8 bnr x 2 wc)

#define LOG2E 1.44269504088896340736f

typedef __attribute__((ext_vector_type(8))) int  i32x8;
typedef __attribute__((ext_vector_type(4))) float f32x4;
typedef unsigned char uchar;

#if __has_builtin(__builtin_amdgcn_exp2f)
#define EXP2(x) __builtin_amdgcn_exp2f(x)   // bare v_exp_f32; |arg|<=1.45 -> exact
#else
#define EXP2(x) exp2f(x)
#endif

__device__ __forceinline__ void gload_lds16(const void* g, void* l) {
  __builtin_amdgcn_global_load_lds(
      (const __attribute__((address_space(1))) void*)g,
      (__attribute__((address_space(3))) void*)l, 16, 0, 0);
}

// Tiled fp8 layout ("frag-major", HW-verified r10-r12): row r, byte (c*32+b):
//   addr = (r>>4)*4096 + c*512 + (r&15)*32 + b
// Wave frag load (lane l: row 16g+(l&15), K-chunk kt*4+(l>>4)) =
//   g*4096 + kt*2048 + l*32  -> 2KB contiguous.

// ---------------- Kernel A: normalize BOTH matrices -> tiled fp8 + diag -----
__global__ void normalize_both(const float* __restrict__ o,
                               const float* __restrict__ t,
                               uchar* __restrict__ o8,
                               uchar* __restrict__ t8,
                               float* __restrict__ dlog) {
  int row  = blockIdx.x * 4 + (threadIdx.x >> 6);
  int lane = threadIdx.x & 63;
  float4 a = *(reinterpret_cast<const float4*>(o + (size_t)row * DIM) + lane);
  float4 b = *(reinterpret_cast<const float4*>(t + (size_t)row * DIM) + lane);
  float sso = a.x * a.x + a.y * a.y + a.z * a.z + a.w * a.w;
  float sst = b.x * b.x + b.y * b.y + b.z * b.z + b.w * b.w;
  float d   = a.x * b.x + a.y * b.y + a.z * b.z + a.w * b.w;
#pragma unroll
  for (int m = 1; m < 64; m <<= 1) {
    sso += __shfl_xor(sso, m);
    sst += __shfl_xor(sst, m);
    d   += __shfl_xor(d, m);
  }
  float ro = rsqrtf(sso);
  float rt = rsqrtf(sst);
  if (lane == 0) dlog[row] = d * ro * rt;
  float qo = ro * LOG2E;
  int wo = 0, wt = 0;
  wo = __builtin_amdgcn_cvt_pk_fp8_f32(a.x * qo, a.y * qo, wo, false);
  wo = __builtin_amdgcn_cvt_pk_fp8_f32(a.z * qo, a.w * qo, wo, true);
  wt = __builtin_amdgcn_cvt_pk_fp8_f32(b.x * rt, b.y * rt, wt, false);
  wt = __builtin_amdgcn_cvt_pk_fp8_f32(b.z * rt, b.w * rt, wt, true);
  size_t taddr = (size_t)(row >> 4) * 4096 + (size_t)((lane >> 3) * 512) +
                 (size_t)((row & 15) * 32) + (size_t)((lane & 7) * 4);
  *reinterpret_cast<int*>(o8 + taddr) = wo;
  *reinterpret_cast<int*>(t8 + taddr) = wt;
}

// ---------------- Kernel B: persistent-A fp8 GEMM, B via LDS ----------------
// Block = 128 A-rows x 2048 cols; 8 waves (4 wr x 2 wc), wave tile 32x64.
// A-frags register-resident (af[2][2]); B staged tile-by-tile (32 KB, all 8
// waves share) via global_load_lds into double-buffered LDS -> B occupies ZERO
// registers (r12's AGPR trap). LDS image per 2KB chunk c (= g*2+kt):
//   lo 16B halves at [c*2048 + l*16], hi halves at [c*2048 + 1024 + l*16]
// (split applied via the gload SOURCE address; dest stays linear) -> fragment
// ds_reads are linear stride-16, conflict-free. One barrier per tile.
// Frag (HW-verified r5/r6/r10-r12): lane l holds row (l&15), K [(l>>4)*32).
// C/D: col = lane&15, row = (lane>>4)*4 + reg.
__global__ __launch_bounds__(512, 4) void gemm_expsum(
    const uchar* __restrict__ A8,   // ohat fp8 tiled, pre-scaled by log2e
    const uchar* __restrict__ B8,   // that fp8 tiled (rows = logits cols)
    float* __restrict__ partial) {
  __shared__ __align__(16) uchar Bs[2][NTILE * 2048];  // 2 x 32 KB

  // XCD-partitioned: xcd owns a contiguous 16-entry bm strip; consecutive ids
  // share bnr -> concurrent blocks on an XCD reuse the same 512KB B strip.
  int b   = blockIdx.x;
  int xcd = b & 7;
  int idx = b >> 3;               // 0..127
  int bm  = xcd * 16 + (idx & 15);
  int bnr = idx >> 4;             // 0..7

  int tid  = threadIdx.x;
  int lane = tid & 63;
  int wid  = tid >> 6;            // 0..7
  int wr   = wid >> 1;            // 0..3 (32-row strip)
  int wc   = wid & 1;             // 0..1 (64-col strip)

  const uchar* Ap = A8 + (size_t)(bm * 8 + wr * 2) * 4096 + (size_t)lane * 32;
  const uchar* Bg = B8 + (size_t)(bnr * 128) * 4096;   // 512 KB strip, tiled

  // persistent A fragments (32 regs; AGPR-resident is fine: MFMA reads direct)
  i32x8 af[2][2];
#pragma unroll
  for (int m = 0; m < 2; ++m)
#pragma unroll
    for (int kt = 0; kt < 2; ++kt)
      af[m][kt] = *reinterpret_cast<const i32x8*>(Ap + m * 4096 + kt * 2048);

  float v[8];
#pragma unroll
  for (int j = 0; j < 8; ++j) v[j] = 0.f;

  const f32x4 zero4 = {0.f, 0.f, 0.f, 0.f};

  // stage tile t into buf s: 4 passes x (512 thr x 16B) = 32 KB.
  // wave wid covers dest [p*8192 + wid*1024): chunk cc = wid>>1, half h = wid&1;
  // src lane byte = cc*2048 + lane*32 + h*16 within the tile's 8KB pass region.
#define STAGE(t, s)                                                            \
  {                                                                            \
    _Pragma("unroll") for (int p = 0; p < 4; ++p)                              \
        gload_lds16(Bg + (size_t)(t) * 32768 + p * 8192 + (wid >> 1) * 2048 +  \
                        lane * 32 + (wid & 1) * 16,                            \
                    (char*)Bs[s] + p * 8192 + wid * 1024);                     \
  }

#define COMPUTE(s)                                                             \
  {                                                                            \
    const uchar* bb = Bs[s];                                                   \
    _Pragma("unroll") for (int n = 0; n < 4; ++n) {                            \
      const uchar* cb = bb + ((wc * 4 + n) * 2) * 2048 + lane * 16;            \
      int4 lo0 = *reinterpret_cast<const int4*>(cb);                           \
      int4 hi0 = *reinterpret_cast<const int4*>(cb + 1024);                    \
      int4 lo1 = *reinterpret_cast<const int4*>(cb + 2048);                    \
      int4 hi1 = *reinterpret_cast<const int4*>(cb + 3072);                    \
      i32x8 b0 = (i32x8){lo0.x, lo0.y, lo0.z, lo0.w, hi0.x, hi0.y, hi0.z, hi0.w}; \
      i32x8 b1 = (i32x8){lo1.x, lo1.y, lo1.z, lo1.w, hi1.x, hi1.y, hi1.z, hi1.w}; \
      _Pragma("unroll") for (int m = 0; m < 2; ++m) {                          \
        f32x4 acc = __builtin_amdgcn_mfma_scale_f32_16x16x128_f8f6f4(          \
            af[m][0], b0, zero4, 0, 0, 0, 0x7F7F7F7F, 0, 0x7F7F7F7F);          \
        acc = __builtin_amdgcn_mfma_scale_f32_16x16x128_f8f6f4(                \
            af[m][1], b1, acc, 0, 0, 0, 0x7F7F7F7F, 0, 0x7F7F7F7F);            \
        v[m * 4 + 0] += EXP2(acc[0]);                                          \
        v[m * 4 + 1] += EXP2(acc[1]);                                          \
        v[m * 4 + 2] += EXP2(acc[2]);                                          \
        v[m * 4 + 3] += EXP2(acc[3]);                                          \
      }                                                                        \
    }                                                                          \
  }

  STAGE(0, 0);
  __syncthreads();                 // tile 0 resident
#pragma unroll
  for (int t = 0; t < NTILE; ++t) {
    if (t < NTILE - 1) STAGE(t + 1, (t + 1) & 1);  // async into other buffer
    COMPUTE(t & 1);
    if (t < NTILE - 1) __syncthreads();  // drain stage(t+1); readers of t done
  }
#undef STAGE
#undef COMPUTE

  // ---- bisect butterfly: v[8] over the 16 fragment columns (r12-verified) ----
#pragma unroll
  for (int s = 0; s < 3; ++s) {
    const int len = 8 >> s;
    const int bit = (lane >> s) & 1;
#pragma unroll
    for (int t = 0; t < 4; ++t) {
      if (t < (len >> 1)) {
        float a = v[2 * t], b2 = v[2 * t + 1];
        float recv = __shfl_xor(bit ? a : b2, 1 << s);
        v[t] = (bit ? b2 : a) + recv;
      }
    }
  }
  v[0] += __shfl_xor(v[0], 8);   // complete the 16-lane column sum
  if ((lane & 8) == 0) {
    int j     = lane & 7;        // m = j>>2, r = j&3
    int sub   = lane >> 4;       // 0..3
    int row   = bm * BM + wr * 32 + (j >> 2) * 16 + sub * 4 + (j & 3);
    int chunk = (bnr << 1) | wc;
    partial[(size_t)row * NCHUNK + chunk] = v[0];
  }
}

// ---------------- Kernel C: per-row finish: log(sum) - exact diag ----------
__global__ void row_finish(const float* __restrict__ partial,
                           const float* __restrict__ dlog,
                           float* __restrict__ rowloss) {
  int tid = threadIdx.x;
  int row = blockIdx.x * 64 + (tid >> 2);
  int q   = tid & 3;
  float4 p = reinterpret_cast<const float4*>(partial + (size_t)row * NCHUNK)[q];
  float s = p.x + p.y + p.z + p.w;
  s += __shfl_xor(s, 1);
  s += __shfl_xor(s, 2);
  if (q == 0) rowloss[row] = logf(s) - dlog[row];
}

// ---------------- Kernel D: mean over rows -> d_out[0] ----------------
__global__ void final_reduce(const float* __restrict__ rl, float* __restrict__ out) {
  __shared__ float sm[16];
  float s = 0.f;
  for (int i = threadIdx.x; i < BROWS; i += 1024) s += rl[i];
#pragma unroll
  for (int m = 1; m < 64; m <<= 1) s += __shfl_xor(s, m);
  int wid = threadIdx.x >> 6, lane = threadIdx.x & 63;
  if (lane == 0) sm[wid] = s;
  __syncthreads();
  if (wid == 0) {
    float v = (lane < 16) ? sm[lane] : 0.f;
#pragma unroll
    for (int m = 1; m < 16; m <<= 1) v += __shfl_xor(v, m);
    if (lane == 0) out[0] = v / (float)BROWS;
  }
}

extern "C" void kernel_launch(void* const* d_in, const int* in_sizes, int n_in,
                              void* d_out, int out_size, void* d_ws, size_t ws_size,
                              hipStream_t stream) {
  const float* outputs = (const float*)d_in[0];
  const float* targets = (const float*)d_in[1];
  float* out = (float*)d_out;
  char* ws = (char*)d_ws;

  uchar* o8      = (uchar*)ws;                                      // 4 MB (tiled)
  uchar* t8      = (uchar*)(ws + (size_t)4 * 1024 * 1024);          // 4 MB (tiled)
  float* partial = (float*)(ws + (size_t)8 * 1024 * 1024);          // 1 MB
  float* dlog    = (float*)(ws + (size_t)10 * 1024 * 1024);         // 64 KB
  float* rowloss = (float*)(ws + (size_t)10 * 1024 * 1024 + 65536); // 64 KB

  normalize_both<<<BROWS / 4, 256, 0, stream>>>(outputs, targets, o8, t8, dlog);
  gemm_expsum<<<NBM * NBNR, 512, 0, stream>>>(o8, t8, partial);
  row_finish<<<BROWS / 64, 256, 0, stream>>>(partial, dlog, rowloss);
  final_reduce<<<1, 1024, 0, stream>>>(rowloss, out);
}

// Round 14
// 78.989 us; speedup vs baseline: 1.1817x; 1.0070x over previous
//
#include <hip/hip_runtime.h>
#include <hip/hip_bf16.h>
#include <stdint.h>

#define BROWS 16384
#define DIM   256
#define BM    128               // A rows per block (persistent in registers)
#define NBM   (BROWS / BM)      // 128 row blocks
#define NBNR  8                 // col-range blocks; each covers 16 tiles x 128
#define NHALF 32                // 64-col half-tiles per block
#define NCHUNK 8                // per-row partial chunks (8 bnr)

#define LOG2E 1.44269504088896340736f

typedef __attribute__((ext_vector_type(8))) int  i32x8;
typedef __attribute__((ext_vector_type(4))) float f32x4;
typedef unsigned char uchar;

#if __has_builtin(__builtin_amdgcn_exp2f)
#define EXP2(x) __builtin_amdgcn_exp2f(x)   // bare v_exp_f32; |arg|<=1.45 -> exact
#else
#define EXP2(x) exp2f(x)
#endif

__device__ __forceinline__ void gload_lds16(const void* g, void* l) {
  __builtin_amdgcn_global_load_lds(
      (const __attribute__((address_space(1))) void*)g,
      (__attribute__((address_space(3))) void*)l, 16, 0, 0);
}

// Tiled fp8 layout ("frag-major", HW-verified r10-r13): row r, byte (c*32+b):
//   addr = (r>>4)*4096 + c*512 + (r&15)*32 + b
// 2KB chunk (g,kt) at (g*2+kt)*2048 within each 16-row group's 4KB... for B
// the block-col strip is 512KB of contiguous 32KB tiles; each 64-col half-tile
// is a contiguous 16KB range.

// ---------------- Kernel A: normalize BOTH matrices -> tiled fp8 + diag -----
__global__ void normalize_both(const float* __restrict__ o,
                               const float* __restrict__ t,
                               uchar* __restrict__ o8,
                               uchar* __restrict__ t8,
                               float* __restrict__ dlog) {
  int row  = blockIdx.x * 4 + (threadIdx.x >> 6);
  int lane = threadIdx.x & 63;
  float4 a = *(reinterpret_cast<const float4*>(o + (size_t)row * DIM) + lane);
  float4 b = *(reinterpret_cast<const float4*>(t + (size_t)row * DIM) + lane);
  float sso = a.x * a.x + a.y * a.y + a.z * a.z + a.w * a.w;
  float sst = b.x * b.x + b.y * b.y + b.z * b.z + b.w * b.w;
  float d   = a.x * b.x + a.y * b.y + a.z * b.z + a.w * b.w;
#pragma unroll
  for (int m = 1; m < 64; m <<= 1) {
    sso += __shfl_xor(sso, m);
    sst += __shfl_xor(sst, m);
    d   += __shfl_xor(d, m);
  }
  float ro = rsqrtf(sso);
  float rt = rsqrtf(sst);
  if (lane == 0) dlog[row] = d * ro * rt;
  float qo = ro * LOG2E;
  int wo = 0, wt = 0;
  wo = __builtin_amdgcn_cvt_pk_fp8_f32(a.x * qo, a.y * qo, wo, false);
  wo = __builtin_amdgcn_cvt_pk_fp8_f32(a.z * qo, a.w * qo, wo, true);
  wt = __builtin_amdgcn_cvt_pk_fp8_f32(b.x * rt, b.y * rt, wt, false);
  wt = __builtin_amdgcn_cvt_pk_fp8_f32(b.z * rt, b.w * rt, wt, true);
  size_t taddr = (size_t)(row >> 4) * 4096 + (size_t)((lane >> 3) * 512) +
                 (size_t)((row & 15) * 32) + (size_t)((lane & 7) * 4);
  *reinterpret_cast<int*>(o8 + taddr) = wo;
  *reinterpret_cast<int*>(t8 + taddr) = wt;
}

// ---------------- Kernel B: persistent-A fp8 GEMM, B via half-tile LDS ------
// Block = 128 A-rows x 2048 cols; 4 waves (wr = wid), wave tile 32 x 64.
// A-frags register-resident (af[2][2]). B staged in 64-col HALF-TILES (16 KB)
// double-buffered -> 32 KB LDS total -> 5 blocks/CU (vs r13's 2). Per-wave
// work identical to r13. LDS image per 2KB chunk: lo 16B halves at [c*2048 +
// l*16], hi at [c*2048 + 1024 + l*16] (split via gload SOURCE; dest linear)
// -> stride-16 ds_read_b128, conflict-free (r13-verified: 0 conflicts).
// Frag (HW-verified r5/r6/r10-r13): lane l holds row (l&15), K [(l>>4)*32).
// C/D: col = lane&15, row = (lane>>4)*4 + reg.
__global__ __launch_bounds__(256, 5) void gemm_expsum(
    const uchar* __restrict__ A8,   // ohat fp8 tiled, pre-scaled by log2e
    const uchar* __restrict__ B8,   // that fp8 tiled (rows = logits cols)
    float* __restrict__ partial) {
  __shared__ __align__(16) uchar Bs[2][16384];  // 2 x 16 KB

  // XCD-partitioned: xcd owns a contiguous 16-entry bm strip; consecutive ids
  // share bnr -> concurrent blocks on an XCD reuse the same 512KB B strip.
  int b   = blockIdx.x;
  int xcd = b & 7;
  int idx = b >> 3;               // 0..127
  int bm  = xcd * 16 + (idx & 15);
  int bnr = idx >> 4;             // 0..7

  int tid  = threadIdx.x;
  int lane = tid & 63;
  int wid  = tid >> 6;            // 0..3 == wr (32-row strip)

  const uchar* Ap = A8 + (size_t)(bm * 8 + wid * 2) * 4096 + (size_t)lane * 32;
  const uchar* Bg = B8 + (size_t)(bnr * 128) * 4096;   // 512 KB strip, tiled

  // persistent A fragments (32 regs)
  i32x8 af[2][2];
#pragma unroll
  for (int m = 0; m < 2; ++m)
#pragma unroll
    for (int kt = 0; kt < 2; ++kt)
      af[m][kt] = *reinterpret_cast<const i32x8*>(Ap + m * 4096 + kt * 2048);

  float v[8];
#pragma unroll
  for (int j = 0; j < 8; ++j) v[j] = 0.f;

  const f32x4 zero4 = {0.f, 0.f, 0.f, 0.f};

  // stage half-tile ht (16KB) into buf s: 4 passes x (256 thr x 16B).
  // pass p: dest [p*4096 + wid*1024): chunk cc = p*2 + (wid>>1), half = wid&1;
  // src byte = ht*16384 + cc*2048 + lane*32 + (wid&1)*16 (lo/hi split at src).
#define STAGE(ht, s)                                                           \
  {                                                                            \
    _Pragma("unroll") for (int p = 0; p < 4; ++p)                              \
        gload_lds16(Bg + (size_t)(ht) * 16384 + (p * 2 + (wid >> 1)) * 2048 +  \
                        lane * 32 + (wid & 1) * 16,                            \
                    (char*)Bs[s] + p * 4096 + wid * 1024);                     \
  }

#define COMPUTE(s)                                                             \
  {                                                                            \
    const uchar* bb = Bs[s];                                                   \
    _Pragma("unroll") for (int n = 0; n < 4; ++n) {                            \
      const uchar* cb = bb + n * 4096 + lane * 16;                             \
      int4 lo0 = *reinterpret_cast<const int4*>(cb);                           \
      int4 hi0 = *reinterpret_cast<const int4*>(cb + 1024);                    \
      int4 lo1 = *reinterpret_cast<const int4*>(cb + 2048);                    \
      int4 hi1 = *reinterpret_cast<const int4*>(cb + 3072);                    \
      i32x8 b0 = (i32x8){lo0.x, lo0.y, lo0.z, lo0.w, hi0.x, hi0.y, hi0.z, hi0.w}; \
      i32x8 b1 = (i32x8){lo1.x, lo1.y, lo1.z, lo1.w, hi1.x, hi1.y, hi1.z, hi1.w}; \
      _Pragma("unroll") for (int m = 0; m < 2; ++m) {                          \
        f32x4 acc = __builtin_amdgcn_mfma_scale_f32_16x16x128_f8f6f4(          \
            af[m][0], b0, zero4, 0, 0, 0, 0x7F7F7F7F, 0, 0x7F7F7F7F);          \
        acc = __builtin_amdgcn_mfma_scale_f32_16x16x128_f8f6f4(                \
            af[m][1], b1, acc, 0, 0, 0, 0x7F7F7F7F, 0, 0x7F7F7F7F);            \
        v[m * 4 + 0] += EXP2(acc[0]);                                          \
        v[m * 4 + 1] += EXP2(acc[1]);                                          \
        v[m * 4 + 2] += EXP2(acc[2]);                                          \
        v[m * 4 + 3] += EXP2(acc[3]);                                          \
      }                                                                        \
    }                                                                          \
  }

  STAGE(0, 0);
  __syncthreads();                 // half-tile 0 resident
#pragma unroll
  for (int ht = 0; ht < NHALF; ++ht) {
    if (ht < NHALF - 1) STAGE(ht + 1, (ht + 1) & 1);  // async into other buffer
    COMPUTE(ht & 1);
    if (ht < NHALF - 1) __syncthreads();  // drain stage(ht+1); readers of ht done
  }
#undef STAGE
#undef COMPUTE

  // ---- bisect butterfly: v[8] over the 16 fragment columns (r12-verified) ----
#pragma unroll
  for (int s = 0; s < 3; ++s) {
    const int len = 8 >> s;
    const int bit = (lane >> s) & 1;
#pragma unroll
    for (int t = 0; t < 4; ++t) {
      if (t < (len >> 1)) {
        float a = v[2 * t], b2 = v[2 * t + 1];
        float recv = __shfl_xor(bit ? a : b2, 1 << s);
        v[t] = (bit ? b2 : a) + recv;
      }
    }
  }
  v[0] += __shfl_xor(v[0], 8);   // complete the 16-lane column sum
  if ((lane & 8) == 0) {
    int j   = lane & 7;          // m = j>>2, r = j&3
    int sub = lane >> 4;         // 0..3
    int row = bm * BM + wid * 32 + (j >> 2) * 16 + sub * 4 + (j & 3);
    partial[(size_t)row * NCHUNK + bnr] = v[0];
  }
}

// ---------------- Kernel C: per-row finish: log(sum) - exact diag ----------
// one thread per row: 8 partials = 2 x float4 (32B contiguous per thread).
__global__ void row_finish(const float* __restrict__ partial,
                           const float* __restrict__ dlog,
                           float* __restrict__ rowloss) {
  int row = blockIdx.x * 256 + threadIdx.x;
  const float4* p = reinterpret_cast<const float4*>(partial + (size_t)row * NCHUNK);
  float4 p0 = p[0], p1 = p[1];
  float s = (p0.x + p0.y + p0.z + p0.w) + (p1.x + p1.y + p1.z + p1.w);
  rowloss[row] = logf(s) - dlog[row];
}

// ---------------- Kernel D: mean over rows -> d_out[0] ----------------
__global__ void final_reduce(const float* __restrict__ rl, float* __restrict__ out) {
  __shared__ float sm[16];
  float s = 0.f;
  for (int i = threadIdx.x; i < BROWS; i += 1024) s += rl[i];
#pragma unroll
  for (int m = 1; m < 64; m <<= 1) s += __shfl_xor(s, m);
  int wid = threadIdx.x >> 6, lane = threadIdx.x & 63;
  if (lane == 0) sm[wid] = s;
  __syncthreads();
  if (wid == 0) {
    float v = (lane < 16) ? sm[lane] : 0.f;
#pragma unroll
    for (int m = 1; m < 16; m <<= 1) v += __shfl_xor(v, m);
    if (lane == 0) out[0] = v / (float)BROWS;
  }
}

extern "C" void kernel_launch(void* const* d_in, const int* in_sizes, int n_in,
                              void* d_out, int out_size, void* d_ws, size_t ws_size,
                              hipStream_t stream) {
  const float* outputs = (const float*)d_in[0];
  const float* targets = (const float*)d_in[1];
  float* out = (float*)d_out;
  char* ws = (char*)d_ws;

  uchar* o8      = (uchar*)ws;                                      // 4 MB (tiled)
  uchar* t8      = (uchar*)(ws + (size_t)4 * 1024 * 1024);          // 4 MB (tiled)
  float* partial = (float*)(ws + (size_t)8 * 1024 * 1024);          // 512 KB
  float* dlog    = (float*)(ws + (size_t)9 * 1024 * 1024);          // 64 KB
  float* rowloss = (float*)(ws + (size_t)9 * 1024 * 1024 + 65536);  // 64 KB

  normalize_both<<<BROWS / 4, 256, 0, stream>>>(outputs, targets, o8, t8, dlog);
  gemm_expsum<<<NBM * NBNR, 256, 0, stream>>>(o8, t8, partial);
  row_finish<<<BROWS / 256, 256, 0, stream>>>(partial, dlog, rowloss);
  final_reduce<<<1, 1024, 0, stream>>>(rowloss, out);
}